// Round 9
// baseline (1823.376 us; speedup 1.0000x reference)
//
#include <hip/hip_runtime.h>
#include <hip/hip_bf16.h>

// Problem constants
#define B_   2048
#define E_   512
#define S_   64
#define K_   1024
#define NG   2048

#define BM 64
#define BN 256

typedef __attribute__((ext_vector_type(8))) short  bfrag8;
typedef __attribute__((ext_vector_type(4))) float  f32x4;

#define WAITVM(N) asm volatile("s_waitcnt vmcnt(" #N ")" ::: "memory")

__device__ __forceinline__ void gload16(const void* g, void* l) {
  __builtin_amdgcn_global_load_lds(
      (const __attribute__((address_space(1))) unsigned int*)g,
      (__attribute__((address_space(3))) unsigned int*)l,
      16, 0, 0);
}

__device__ __forceinline__ float sigm(float x)      { return 1.f / (1.f + __expf(-x)); }
__device__ __forceinline__ float tanh_fast(float x) { return 2.f / (1.f + __expf(-2.f * x)) - 1.f; }

// Gate-interleaved permutation for BN=256 blocks (8 te x 4 waves x 4 gates x 16):
//   p = te*256 + c;  c = w*64 + g*16 + q  ->  e = te*64 + w*16 + q, n = g*512 + e
__global__ __launch_bounds__(256) void prep_weights(
    const float* __restrict__ Wih, const float* __restrict__ Whh,
    const float* __restrict__ bih, const float* __restrict__ bhh,
    __hip_bfloat16* __restrict__ Wp, float* __restrict__ biasP)
{
  int p  = blockIdx.x;
  int te = p >> 8;
  int c  = p & 255;
  int w  = c >> 6;
  int g  = (c >> 4) & 3;
  int q  = c & 15;
  int e  = te * 64 + w * 16 + q;
  int n  = g * E_ + e;
  const float* s0 = Wih + (size_t)n * E_;
  const float* s1 = Whh + (size_t)n * E_;
  __hip_bfloat16* dst = Wp + (size_t)p * K_;
  for (int k = threadIdx.x; k < E_; k += 256) {
    dst[k]       = __float2bfloat16(s0[k]);
    dst[E_ + k]  = __float2bfloat16(s1[k]);
  }
  if (threadIdx.x == 0) biasP[p] = bih[n] + bhh[n];
}

// Xe[t][b][e] = bf16(emb[x[b][t]][e])  -- one-time gather (verified r6)
__global__ __launch_bounds__(256) void pregather(
    const int* __restrict__ x, const float* __restrict__ emb,
    __hip_bfloat16* __restrict__ Xe)
{
  int row  = blockIdx.x * 4 + (threadIdx.x >> 6);   // row = b*64 + t
  int lane = threadIdx.x & 63;
  int b = row >> 6, t = row & 63;
  size_t xi = (size_t)x[row];
  const float* src = emb + xi * E_ + lane * 8;
  float4 f0 = *(const float4*)(src);
  float4 f1 = *(const float4*)(src + 4);
  union { __hip_bfloat16 h[8]; uint4 v; } u;
  u.h[0] = __float2bfloat16(f0.x); u.h[1] = __float2bfloat16(f0.y);
  u.h[2] = __float2bfloat16(f0.z); u.h[3] = __float2bfloat16(f0.w);
  u.h[4] = __float2bfloat16(f1.x); u.h[5] = __float2bfloat16(f1.y);
  u.h[6] = __float2bfloat16(f1.z); u.h[7] = __float2bfloat16(f1.w);
  *(uint4*)(Xe + ((size_t)t * B_ + b) * E_ + lane * 8) = u.v;
}

// One LSTM timestep. 256 blocks (te=blk&7 -> per-XCD L2-resident B; tm=blk>>3).
// 4 waves: wave wc owns cols wc*64..+64 of the 256-col tile, all 64 rows.
// A (64 x 1024: [Xe[t] | Hprev]) staged via LDS ring ND=4; B global->regs.
__global__ __launch_bounds__(256) void lstm_step(
    const __hip_bfloat16* __restrict__ Xe,     // [64][2048][512]
    const __hip_bfloat16* __restrict__ Hp,     // [2048][512] bf16
    __hip_bfloat16* __restrict__ Hn,           // [2048][512] bf16
    const __hip_bfloat16* __restrict__ Wp,     // [2048][1024] permuted
    const float* __restrict__ biasP,           // [2048]
    float* __restrict__ c,                     // [2048][512] fp32
    float* __restrict__ out,                   // [2048][512] fp32
    int t)
{
  __shared__ __hip_bfloat16 As[4][BM * 64];    // 4 x 8 KB ring

  const int tid = threadIdx.x;
  const int te  = blockIdx.x & 7;
  const int tm  = blockIdx.x >> 3;             // 0..31

  const int wc = tid >> 6, l = tid & 63;
  const int lq = l & 15,  lh = l >> 4;

  const int arow0 = tm * BM;
  const int brow0 = te * BN;
  const int e     = te * 64 + wc * 16 + lq;

  // ---- misc prologue loads ----
  float bg[4];
#pragma unroll
  for (int n = 0; n < 4; ++n)
    bg[n] = biasP[brow0 + wc * 64 + n * 16 + lq];

  float cold[4][4];
#pragma unroll
  for (int m = 0; m < 4; ++m)
#pragma unroll
    for (int r = 0; r < 4; ++r)
      cold[m][r] = c[(size_t)(arow0 + m * 16 + lh * 4 + r) * E_ + e];
  __builtin_amdgcn_sched_barrier(0);

  // B row base pointers (all later offsets are compile-time immediates)
  const __hip_bfloat16* bb[4];
#pragma unroll
  for (int n = 0; n < 4; ++n)
    bb[n] = Wp + (size_t)(brow0 + wc * 64 + n * 16 + lq) * K_ + lh * 8;

  // A fragment LDS offsets (verified zero-conflict involution swizzle)
  int aoff[2][4];
#pragma unroll
  for (int ks = 0; ks < 2; ++ks)
#pragma unroll
    for (int m = 0; m < 4; ++m) {
      int cl = (m * 16 + lq) * 8 + ks * 4 + lh;
      aoff[ks][m] = (cl ^ ((cl >> 3) & 7)) * 8;
    }

  // A staging: 512 chunks of 16B; dest linear, source involution-swizzled
  auto stageA = [&](int kt, int buf) {
#pragma unroll
    for (int it = 0; it < 2; ++it) {
      int ch  = it * 256 + tid;
      int cl  = ch ^ ((ch >> 3) & 7);
      int row = cl >> 3, gr = cl & 7;
      const __hip_bfloat16* src = (kt < 8)
        ? Xe + ((size_t)t * B_ + arow0 + row) * E_ + kt * 64 + gr * 8
        : Hp + (size_t)(arow0 + row) * E_ + (kt - 8) * 64 + gr * 8;
      gload16(src, &As[buf][ch * 8]);
    }
  };

  f32x4 acc[4][4];
#pragma unroll
  for (int m = 0; m < 4; ++m)
#pragma unroll
    for (int n = 0; n < 4; ++n)
      acc[m][n] = (f32x4){0.f, 0.f, 0.f, 0.f};

  bfrag8 Ba[8], Bb2[8];

#define LOADB(KT, BR) do {                                                  \
  _Pragma("unroll") for (int ks = 0; ks < 2; ++ks)                          \
    _Pragma("unroll") for (int n = 0; n < 4; ++n)                           \
      BR[ks * 4 + n] = *(const bfrag8*)(bb[n] + (KT) * 64 + ks * 32);       \
} while (0)

#define MFMAI(RB, BR) do {                                                  \
  _Pragma("unroll") for (int ks = 0; ks < 2; ++ks) {                        \
    bfrag8 af[4];                                                           \
    _Pragma("unroll") for (int m = 0; m < 4; ++m)                           \
      af[m] = *(const bfrag8*)(&As[RB][aoff[ks][m]]);                       \
    __builtin_amdgcn_s_setprio(1);                                          \
    _Pragma("unroll") for (int m = 0; m < 4; ++m)                           \
      _Pragma("unroll") for (int n = 0; n < 4; ++n)                         \
        acc[m][n] = __builtin_amdgcn_mfma_f32_16x16x32_bf16(                \
            af[m], BR[ks * 4 + n], acc[m][n], 0, 0, 0);                     \
    __builtin_amdgcn_s_setprio(0);                                          \
  }                                                                         \
} while (0)

#define SBAR() do { __builtin_amdgcn_s_barrier(); __builtin_amdgcn_sched_barrier(0); } while (0)

  // prologue: queue = [misc, A0, A1, B0, A2]
  stageA(0, 0); stageA(1, 1);
  LOADB(0, Ba);
  stageA(2, 2);
  __builtin_amdgcn_sched_barrier(0);

  // Steady iter kt: WAITVM(2) completes A(kt+1),B(kt), leaves A(kt+2);
  // then issue B(kt+1), A(kt+3).  A slack ~2 iters (L3-safe), B ~1 (L2-safe).
#define ITER(KT, WN, BCUR, BNXT, DOSTAGE, DOLOADB) do {                     \
  WAITVM(WN); SBAR();                                                       \
  if (DOLOADB) LOADB((KT) + 1, BNXT);                                       \
  if (DOSTAGE) stageA((KT) + 3, ((KT) + 3) & 3);                            \
  MFMAI((KT) & 3, BCUR);                                                    \
} while (0)

  ITER(0, 2, Ba, Bb2, 1, 1);
  ITER(1, 2, Bb2, Ba, 1, 1);
  ITER(2, 2, Ba, Bb2, 1, 1);
  ITER(3, 2, Bb2, Ba, 1, 1);
  ITER(4, 2, Ba, Bb2, 1, 1);
  ITER(5, 2, Bb2, Ba, 1, 1);
  ITER(6, 2, Ba, Bb2, 1, 1);
  ITER(7, 2, Bb2, Ba, 1, 1);
  ITER(8, 2, Ba, Bb2, 1, 1);
  ITER(9, 2, Bb2, Ba, 1, 1);
  ITER(10, 2, Ba, Bb2, 1, 1);
  ITER(11, 2, Bb2, Ba, 1, 1);
  ITER(12, 2, Ba, Bb2, 1, 1);
  ITER(13, 2, Bb2, Ba, 0, 1);
  ITER(14, 0, Ba, Bb2, 0, 1);
  ITER(15, 0, Bb2, Ba, 0, 0);

#undef ITER
#undef SBAR
#undef MFMAI
#undef LOADB

  // ---- register epilogue ----
  const bool last = (t == S_ - 1);
#pragma unroll
  for (int m = 0; m < 4; ++m) {
#pragma unroll
    for (int r = 0; r < 4; ++r) {
      int b = arow0 + m * 16 + lh * 4 + r;
      float iv = acc[m][0][r] + bg[0];
      float fv = acc[m][1][r] + bg[1];
      float gv = acc[m][2][r] + bg[2];
      float ov = acc[m][3][r] + bg[3];
      size_t idx = (size_t)b * E_ + e;
      float ig = sigm(iv), fg = sigm(fv), gg = tanh_fast(gv), og = sigm(ov);
      float cn = fg * cold[m][r] + ig * gg;
      c[idx] = cn;
      float h = og * tanh_fast(cn);
      if (last) out[idx] = h;
      else      Hn[idx]  = __float2bfloat16(h);
    }
  }
}

extern "C" void kernel_launch(void* const* d_in, const int* in_sizes, int n_in,
                              void* d_out, int out_size, void* d_ws, size_t ws_size,
                              hipStream_t stream) {
  const int*   x   = (const int*)d_in[0];
  const float* emb = (const float*)d_in[1];
  const float* Wih = (const float*)d_in[2];
  const float* Whh = (const float*)d_in[3];
  const float* bih = (const float*)d_in[4];
  const float* bhh = (const float*)d_in[5];
  float* out = (float*)d_out;
  (void)in_sizes; (void)n_in; (void)out_size; (void)ws_size;

  char* p = (char*)d_ws;
  __hip_bfloat16* Wp    = (__hip_bfloat16*)p;  p += (size_t)NG * K_ * 2;        // 4 MB
  float*          biasP = (float*)p;           p += (size_t)NG * 4;             // 8 KB
  __hip_bfloat16* Xe    = (__hip_bfloat16*)p;  p += (size_t)S_ * B_ * E_ * 2;   // 128 MB
  __hip_bfloat16* H0    = (__hip_bfloat16*)p;  p += (size_t)B_ * E_ * 2;        // 2 MB
  __hip_bfloat16* H1    = (__hip_bfloat16*)p;  p += (size_t)B_ * E_ * 2;        // 2 MB
  float*          c     = (float*)p;           p += (size_t)B_ * E_ * 4;        // 4 MB

  prep_weights<<<NG, 256, 0, stream>>>(Wih, Whh, bih, bhh, Wp, biasP);
  pregather<<<(B_ * S_) / 4, 256, 0, stream>>>(x, emb, Xe);
  hipMemsetAsync(H0, 0, (size_t)B_ * E_ * 2, stream);
  hipMemsetAsync(c,  0, (size_t)B_ * E_ * 4, stream);
  for (int t = 0; t < S_; ++t) {
    const __hip_bfloat16* Hprev = (t & 1) ? H1 : H0;
    __hip_bfloat16*       Hnext = (t & 1) ? H0 : H1;
    lstm_step<<<256, 256, 0, stream>>>(Xe, Hprev, Hnext, Wp, biasP, c, out, t);
  }
}

// Round 12
// 1647.505 us; speedup vs baseline: 1.1067x; 1.1067x over previous
//
#include <hip/hip_runtime.h>
#include <hip/hip_bf16.h>

#define B_ 2048
#define E_ 512
#define S_ 64
#define K_ 1024
#define NG 2048
#define GS 9          // Gx ring slots (8 in flight + 1; 8 % 9 != 0 -> no alias)

typedef __attribute__((ext_vector_type(8))) short bfrag8;
typedef __attribute__((ext_vector_type(4))) float f32x4;

#define WAITVM(N) asm volatile("s_waitcnt vmcnt(" #N ")" ::: "memory")
#define SBAR() do { __builtin_amdgcn_s_barrier(); __builtin_amdgcn_sched_barrier(0); } while (0)

__device__ __forceinline__ void gload16(const void* g, void* l) {
  __builtin_amdgcn_global_load_lds(
      (const __attribute__((address_space(1))) unsigned int*)g,
      (__attribute__((address_space(3))) unsigned int*)l,
      16, 0, 0);
}

__device__ __forceinline__ float sigm(float x)      { return 1.f / (1.f + __expf(-x)); }
__device__ __forceinline__ float tanh_fast(float x) { return 2.f / (1.f + __expf(-2.f * x)) - 1.f; }

// Gate-interleaved permutation (verified r4-r8).
// p: te=p>>7, c=p&127 = hi*64 + g*16 + q ; e = te*32+hi*16+q ; n = g*512+e
// Wp[p][0:512]=W_ih[n], Wp[p][512:1024]=W_hh[n]
__global__ __launch_bounds__(256) void prep_weights(
    const float* __restrict__ Wih, const float* __restrict__ Whh,
    const float* __restrict__ bih, const float* __restrict__ bhh,
    __hip_bfloat16* __restrict__ Wp, float* __restrict__ biasP)
{
  int p  = blockIdx.x;
  int te = p >> 7;
  int c  = p & 127;
  int hi = (c >> 6) & 1;
  int g  = (c >> 4) & 3;
  int q  = c & 15;
  int e  = te * 32 + hi * 16 + q;
  int n  = g * E_ + e;
  const float* s0 = Wih + (size_t)n * E_;
  const float* s1 = Whh + (size_t)n * E_;
  __hip_bfloat16* dst = Wp + (size_t)p * K_;
  for (int k = threadIdx.x; k < E_; k += 256) {
    dst[k]       = __float2bfloat16(s0[k]);
    dst[E_ + k]  = __float2bfloat16(s1[k]);
  }
  if (threadIdx.x == 0) biasP[p] = bih[n] + bhh[n];
}

// ---- helper: one 128x128 tile of Gx[tt] = xe(tt) @ Wih_p^T + bias ----
// Simple double-buffered reg-staged GEMM (swizzled LDS), K=512, BK=32.
__device__ __forceinline__ void xgemm_tile(
    int tt, int job, const int* __restrict__ x, const float* __restrict__ emb,
    const __hip_bfloat16* __restrict__ Wp, const float* __restrict__ biasP,
    float* __restrict__ Gx, char* lds)
{
  int* idx = (int*)lds;                                   // [128]
  __hip_bfloat16* As = (__hip_bfloat16*)(lds + 512);      // [2][4096]
  __hip_bfloat16* Bs = As + 2 * 4096;                     // [2][4096]
  const int tid = threadIdx.x;
  const int htm = job & 15, hte = job >> 4;
  if (tid < 128) idx[tid] = x[(size_t)(htm * 128 + tid) * S_ + tt];
  __syncthreads();
  const int w = tid >> 6, l = tid & 63;
  const int wr = w >> 1, wc = w & 1, lq = l & 15, lh = l >> 4;

  float bg[4];
#pragma unroll
  for (int n = 0; n < 4; ++n) bg[n] = biasP[hte * 128 + wc * 64 + n * 16 + lq];

  int aoff[4], boff[4];
#pragma unroll
  for (int m = 0; m < 4; ++m) { int cl = (wr*64 + m*16 + lq)*4 + lh; aoff[m] = (cl ^ ((cl>>3)&7)) * 8; }
#pragma unroll
  for (int n = 0; n < 4; ++n) { int cl = (wc*64 + n*16 + lq)*4 + lh; boff[n] = (cl ^ ((cl>>3)&7)) * 8; }

  f32x4 acc[4][4];
#pragma unroll
  for (int m = 0; m < 4; ++m)
#pragma unroll
    for (int n = 0; n < 4; ++n) acc[m][n] = (f32x4){0.f, 0.f, 0.f, 0.f};

  auto stage = [&](int kt, int buf) {
#pragma unroll
    for (int it = 0; it < 2; ++it) {
      int cl = it * 256 + tid;               // logical 16B chunk 0..511
      int row = cl >> 2, j = cl & 3;
      const float* s = emb + (size_t)idx[row] * E_ + kt * 32 + j * 8;
      float4 f0 = *(const float4*)s;
      float4 f1 = *(const float4*)(s + 4);
      union { __hip_bfloat16 h[8]; uint4 v; } u;
      u.h[0]=__float2bfloat16(f0.x); u.h[1]=__float2bfloat16(f0.y);
      u.h[2]=__float2bfloat16(f0.z); u.h[3]=__float2bfloat16(f0.w);
      u.h[4]=__float2bfloat16(f1.x); u.h[5]=__float2bfloat16(f1.y);
      u.h[6]=__float2bfloat16(f1.z); u.h[7]=__float2bfloat16(f1.w);
      int pc = cl ^ ((cl >> 3) & 7);
      *(uint4*)&As[buf * 4096 + pc * 8] = u.v;
      *(uint4*)&Bs[buf * 4096 + pc * 8] =
          *(const uint4*)(Wp + (size_t)(hte * 128 + row) * K_ + kt * 32 + j * 8);
    }
  };

  stage(0, 0);
  __syncthreads();
#pragma unroll 1
  for (int kt = 0; kt < 16; ++kt) {
    if (kt + 1 < 16) stage(kt + 1, (kt + 1) & 1);
    const __hip_bfloat16* Ab = As + (kt & 1) * 4096;
    const __hip_bfloat16* Bb = Bs + (kt & 1) * 4096;
    bfrag8 af[4], bf[4];
#pragma unroll
    for (int m = 0; m < 4; ++m) af[m] = *(const bfrag8*)(Ab + aoff[m]);
#pragma unroll
    for (int n = 0; n < 4; ++n) bf[n] = *(const bfrag8*)(Bb + boff[n]);
#pragma unroll
    for (int m = 0; m < 4; ++m)
#pragma unroll
      for (int n = 0; n < 4; ++n)
        acc[m][n] = __builtin_amdgcn_mfma_f32_16x16x32_bf16(af[m], bf[n], acc[m][n], 0, 0, 0);
    __syncthreads();
  }

  float* g = Gx + (size_t)(tt % GS) * ((size_t)B_ * NG);
#pragma unroll
  for (int m = 0; m < 4; ++m)
#pragma unroll
    for (int r = 0; r < 4; ++r) {
      size_t b = (size_t)(htm * 128 + wr * 64 + m * 16 + lh * 4 + r);
#pragma unroll
      for (int n = 0; n < 4; ++n)
        g[b * NG + hte * 128 + wc * 64 + n * 16 + lq] = acc[m][n][r] + bg[n];
    }
}

// warmup: steps 0..7 (8 x 256 tile jobs)
__global__ __launch_bounds__(256) void xwarm(
    const int* __restrict__ x, const float* __restrict__ emb,
    const __hip_bfloat16* __restrict__ Wp, const float* __restrict__ biasP,
    float* __restrict__ Gx)
{
  __shared__ char lds[512 + 4 * 4096 * 2];
  xgemm_tile(blockIdx.x >> 8, blockIdx.x & 255, x, emb, Wp, biasP, Gx, lds);
}

// Fused launch: blocks 0..255 serial step t (K=512 h-GEMM + cell update);
// blocks 256..511 helper: Gx for step t+8 (fills serial stall bubbles).
__global__ __launch_bounds__(256) void lstm_fused(
    const __hip_bfloat16* __restrict__ Wp, const float* __restrict__ biasP,
    float* __restrict__ Gx,
    const __hip_bfloat16* __restrict__ Hp, __hip_bfloat16* __restrict__ Hn,
    float* __restrict__ c, const int* __restrict__ x,
    const float* __restrict__ emb, float* __restrict__ out, int t)
{
  __shared__ char lds[65536];

  if (blockIdx.x >= 256) {
    int tt = t + 8;
    if (tt < S_) xgemm_tile(tt, blockIdx.x - 256, x, emb, Wp, biasP, Gx, lds);
    return;
  }

  // ---- serial role: gates_h = Hp @ Whh_p^T  (M=128, N=128, K=512) ----
  __hip_bfloat16* As = (__hip_bfloat16*)lds;   // [4][4096]
  __hip_bfloat16* Bs = As + 4 * 4096;          // [4][4096]
  const int tid = threadIdx.x;
  const int s  = blockIdx.x;
  const int tm = s & 15, te = s >> 4;          // tm low bits -> XCD locality for H
  const int arow0 = tm * 128, brow0 = te * 128;
  const int w = tid >> 6, l = tid & 63;
  const int wr = w >> 1, wc = w & 1, lq = l & 15, lh = l >> 4;
  const int e = te * 32 + wc * 16 + lq;

  int aoff[4], boff[4];
#pragma unroll
  for (int m = 0; m < 4; ++m) { int cl = (wr*64 + m*16 + lq)*4 + lh; aoff[m] = (cl ^ ((cl>>3)&7)) * 8; }
#pragma unroll
  for (int n = 0; n < 4; ++n) { int cl = (wc*64 + n*16 + lq)*4 + lh; boff[n] = (cl ^ ((cl>>3)&7)) * 8; }

  // staging: dest chunk linear (gload_lds rule); source = involution(ch)
  auto stageA = [&](int kt, int buf) {
#pragma unroll
    for (int it = 0; it < 2; ++it) {
      int ch = it * 256 + tid;
      int cl = ch ^ ((ch >> 3) & 7);
      int row = cl >> 2, gr = cl & 3;
      gload16(Hp + (size_t)(arow0 + row) * E_ + kt * 32 + gr * 8, &As[buf * 4096 + ch * 8]);
    }
  };
  auto stageB = [&](int kt, int buf) {
#pragma unroll
    for (int it = 0; it < 2; ++it) {
      int ch = it * 256 + tid;
      int cl = ch ^ ((ch >> 3) & 7);
      int row = cl >> 2, gr = cl & 3;
      gload16(Wp + (size_t)(brow0 + row) * K_ + E_ + kt * 32 + gr * 8, &Bs[buf * 4096 + ch * 8]);
    }
  };

  f32x4 acc[4][4];
#pragma unroll
  for (int m = 0; m < 4; ++m)
#pragma unroll
    for (int n = 0; n < 4; ++n) acc[m][n] = (f32x4){0.f, 0.f, 0.f, 0.f};

  auto mfma_iter = [&](int rb) {
    const __hip_bfloat16* Ab = As + rb * 4096;
    const __hip_bfloat16* Bb = Bs + rb * 4096;
    bfrag8 af[4], bf[4];
#pragma unroll
    for (int m = 0; m < 4; ++m) af[m] = *(const bfrag8*)(Ab + aoff[m]);
#pragma unroll
    for (int n = 0; n < 4; ++n) bf[n] = *(const bfrag8*)(Bb + boff[n]);
    __builtin_amdgcn_s_setprio(1);
#pragma unroll
    for (int m = 0; m < 4; ++m)
#pragma unroll
      for (int n = 0; n < 4; ++n)
        acc[m][n] = __builtin_amdgcn_mfma_f32_16x16x32_bf16(af[m], bf[n], acc[m][n], 0, 0, 0);
    __builtin_amdgcn_s_setprio(0);
  };

  // prologue: tiles 0..2 (4 loads/thread each)
  stageA(0, 0); stageB(0, 0);
  stageA(1, 1); stageB(1, 1);
  stageA(2, 2); stageB(2, 2);
  __builtin_amdgcn_sched_barrier(0);

  // ledger: queue = [t0 4, t1 4, t2 4] = 12; steady WAITVM(8) => tile kt done
  WAITVM(8); SBAR(); stageA(3, 3); stageB(3, 3); mfma_iter(0);
#pragma unroll 1
  for (int kt = 1; kt <= 12; ++kt) {
    WAITVM(8); SBAR();
    stageA(kt + 3, (kt + 3) & 3); stageB(kt + 3, (kt + 3) & 3);
    mfma_iter(kt & 3);
  }
  WAITVM(8); SBAR(); mfma_iter(13 & 3);
  WAITVM(4); SBAR(); mfma_iter(14 & 3);
  WAITVM(0); SBAR(); mfma_iter(15 & 3);

  // ---- epilogue: fetch Gx tile (bias folded) + cold c, cell update ----
  const float* g = Gx + (size_t)(t % GS) * ((size_t)B_ * NG);
  float gx[4][4][4], cold[4][4];
#pragma unroll
  for (int m = 0; m < 4; ++m)
#pragma unroll
    for (int r = 0; r < 4; ++r) {
      size_t b = (size_t)(arow0 + wr * 64 + m * 16 + lh * 4 + r);
      cold[m][r] = c[b * E_ + e];
#pragma unroll
      for (int n = 0; n < 4; ++n)
        gx[m][n][r] = g[b * NG + brow0 + wc * 64 + n * 16 + lq];
    }

  const bool last = (t == S_ - 1);
#pragma unroll
  for (int m = 0; m < 4; ++m) {
#pragma unroll
    for (int r = 0; r < 4; ++r) {
      size_t b = (size_t)(arow0 + wr * 64 + m * 16 + lh * 4 + r);
      float iv = acc[m][0][r] + gx[m][0][r];
      float fv = acc[m][1][r] + gx[m][1][r];
      float gv = acc[m][2][r] + gx[m][2][r];
      float ov = acc[m][3][r] + gx[m][3][r];
      size_t idx = b * E_ + e;
      float ig = sigm(iv), fg = sigm(fv), gg = tanh_fast(gv), og = sigm(ov);
      float cn = fg * cold[m][r] + ig * gg;
      c[idx] = cn;
      float h = og * tanh_fast(cn);
      if (last) out[idx] = h;
      else      Hn[idx]  = __float2bfloat16(h);
    }
  }
}

extern "C" void kernel_launch(void* const* d_in, const int* in_sizes, int n_in,
                              void* d_out, int out_size, void* d_ws, size_t ws_size,
                              hipStream_t stream) {
  const int*   x   = (const int*)d_in[0];
  const float* emb = (const float*)d_in[1];
  const float* Wih = (const float*)d_in[2];
  const float* Whh = (const float*)d_in[3];
  const float* bih = (const float*)d_in[4];
  const float* bhh = (const float*)d_in[5];
  float* out = (float*)d_out;
  (void)in_sizes; (void)n_in; (void)out_size; (void)ws_size;

  char* p = (char*)d_ws;
  __hip_bfloat16* Wp    = (__hip_bfloat16*)p;  p += (size_t)NG * K_ * 2;            // 4 MB
  float*          biasP = (float*)p;           p += (size_t)NG * 4;                 // 8 KB
  float*          Gx    = (float*)p;           p += (size_t)GS * B_ * NG * 4;       // 144 MB
  __hip_bfloat16* H0    = (__hip_bfloat16*)p;  p += (size_t)B_ * E_ * 2;            // 2 MB
  __hip_bfloat16* H1    = (__hip_bfloat16*)p;  p += (size_t)B_ * E_ * 2;            // 2 MB
  float*          c     = (float*)p;           p += (size_t)B_ * E_ * 4;            // 4 MB

  prep_weights<<<NG, 256, 0, stream>>>(Wih, Whh, bih, bhh, Wp, biasP);
  hipMemsetAsync(H0, 0, (size_t)B_ * E_ * 2, stream);
  hipMemsetAsync(c,  0, (size_t)B_ * E_ * 4, stream);
  xwarm<<<8 * 256, 256, 0, stream>>>(x, emb, Wp, biasP, Gx);
  for (int t = 0; t < S_; ++t) {
    const __hip_bfloat16* Hp = (t & 1) ? H1 : H0;
    __hip_bfloat16*       Hn = (t & 1) ? H0 : H1;
    lstm_fused<<<512, 256, 0, stream>>>(Wp, biasP, Gx, Hp, Hn, c, x, emb, out, t);
  }
}

// Round 15
// 1219.504 us; speedup vs baseline: 1.4952x; 1.3510x over previous
//
#include <hip/hip_runtime.h>
#include <hip/hip_bf16.h>

// Problem constants
#define B_   2048   // batch
#define E_   512    // embedding / hidden
#define S_   64     // sequence length
#define K_   1024   // fused GEMM K = E (x part) + E (h part)
#define NG   2048   // 4*E gate rows

#define BM 128
#define BN 128
#define BK 64
#define ND  4         // LDS ring depth (prefetch distance 3)

typedef __attribute__((ext_vector_type(8))) short  bfrag8;
typedef __attribute__((ext_vector_type(4))) float  f32x4;

#define WAITVM(N) asm volatile("s_waitcnt vmcnt(" #N ")" ::: "memory")
#define SBAR() do { __builtin_amdgcn_s_barrier(); __builtin_amdgcn_sched_barrier(0); } while (0)

__device__ __forceinline__ void gload16(const void* g, void* l) {
  __builtin_amdgcn_global_load_lds(
      (const __attribute__((address_space(1))) unsigned int*)g,
      (__attribute__((address_space(3))) unsigned int*)l,
      16, 0, 0);
}

__device__ __forceinline__ float sigm(float x)      { return 1.f / (1.f + __expf(-x)); }
__device__ __forceinline__ float tanh_fast(float x) { return 2.f / (1.f + __expf(-2.f * x)) - 1.f; }

// Gate-interleaved permutation (verified rounds 1-12).
// Permuted row p: te = p>>7, c = p&127 = hi*64 + g*16 + q
//   e = te*32 + hi*16 + q ; original gate row n = g*512 + e
__global__ __launch_bounds__(256) void prep_weights(
    const float* __restrict__ Wih, const float* __restrict__ Whh,
    const float* __restrict__ bih, const float* __restrict__ bhh,
    __hip_bfloat16* __restrict__ Wp, float* __restrict__ biasP)
{
  int p  = blockIdx.x;
  int te = p >> 7;
  int c  = p & 127;
  int hi = (c >> 6) & 1;
  int g  = (c >> 4) & 3;
  int q  = c & 15;
  int e  = te * 32 + hi * 16 + q;
  int n  = g * E_ + e;
  const float* s0 = Wih + (size_t)n * E_;
  const float* s1 = Whh + (size_t)n * E_;
  __hip_bfloat16* dst = Wp + (size_t)p * K_;
  for (int k = threadIdx.x; k < E_; k += 256) {
    dst[k]       = __float2bfloat16(s0[k]);
    dst[E_ + k]  = __float2bfloat16(s1[k]);
  }
  if (threadIdx.x == 0) biasP[p] = bih[n] + bhh[n];
}

// c = 0; A0[b][0:512] = bf16(emb[x[b][0]]); A0[b][512:1024] = 0 (h0 = 0)
__global__ __launch_bounds__(256) void init_state(
    const int* __restrict__ x, const float* __restrict__ emb,
    float* __restrict__ c, __hip_bfloat16* __restrict__ A0)
{
  int b  = blockIdx.x;
  int xi = x[(size_t)b * S_ + 0];
  const float* e = emb + (size_t)xi * E_;
  __hip_bfloat16* a = A0 + (size_t)b * K_;
  float* cr = c + (size_t)b * E_;
  for (int k = threadIdx.x; k < E_; k += 256) {
    a[k]       = __float2bfloat16(e[k]);
    a[E_ + k]  = __float2bfloat16(0.f);
    cr[k]      = 0.f;
  }
}

// One fused LSTM timestep. 8 waves/block (2 waves/SIMD for latency hiding).
// Wave tile 32x64 (acc[2][4]); 128x128 block tile, BK=64, ND=4, distance 3.
// 16B-chunk involution swizzle (verified 0-conflict): cl = ch ^ ((ch>>3)&7).
__global__ __launch_bounds__(512, 1) void lstm_step(
    const __hip_bfloat16* __restrict__ Acur,   // [2048][1024] bf16
    __hip_bfloat16* __restrict__ Anext,        // [2048][1024] bf16
    const __hip_bfloat16* __restrict__ Wp,     // [2048][1024] bf16 (permuted)
    const float* __restrict__ biasP,           // [2048] permuted
    float* __restrict__ c,                     // [2048][512] fp32
    const int* __restrict__ x,                 // [2048][64] int32
    const float* __restrict__ emb,             // [32000][512] fp32
    float* __restrict__ out,                   // [2048][512] fp32
    int t)
{
  __shared__ __hip_bfloat16 As[ND][BM * BK];   // 4 x 16 KB
  __shared__ __hip_bfloat16 Bs[ND][BN * BK];   // 4 x 16 KB  (128 KB total)

  const int tid = threadIdx.x;
  // 256 blocks = 16 tm x 16 te; XCD-chunked: per XCD 8 tm x 4 te
  const int x7 = blockIdx.x & 7;
  const int i  = blockIdx.x >> 3;              // 0..31
  const int tm = (x7 & 1) * 8 + (i & 7);       // 0..15
  const int te = (x7 >> 1) * 4 + (i >> 3);     // 0..15

  const int w  = tid >> 6, l = tid & 63;
  const int wr = w >> 1;                       // 0..3: 32-row band
  const int wc = w & 1;                        // 0..1: 64-col half
  const int lq = l & 15, lh = l >> 4;

  const int arow0 = tm * BM;
  const int brow0 = te * BN;
  const int e     = te * 32 + wc * 16 + lq;

  // ---- prologue loads: bias(4), cold c(8), next-step indices(8) = 20 ----
  float bg[4];
#pragma unroll
  for (int n = 0; n < 4; ++n)
    bg[n] = biasP[te * 128 + wc * 64 + n * 16 + lq];

  float cold[2][4];
  int   xiv[2][4];
  const int tn = (t < S_ - 1) ? t + 1 : S_ - 1;
#pragma unroll
  for (int m = 0; m < 2; ++m)
#pragma unroll
    for (int r = 0; r < 4; ++r) {
      int b = arow0 + wr * 32 + m * 16 + lh * 4 + r;
      cold[m][r] = c[(size_t)b * E_ + e];
      xiv[m][r]  = x[(size_t)b * S_ + tn];
    }
  __builtin_amdgcn_sched_barrier(0);

  // staging: 1024 chunks of 16B per tile; dest linear (gload_lds rule),
  // source = involution-swizzled chunk (row = cl>>3, k-chunk = cl&7)
  auto stageA = [&](int kt, int buf) {
    const int k0 = kt * BK;
#pragma unroll
    for (int it = 0; it < 2; ++it) {
      int ch  = it * 512 + tid;                // 0..1023
      int cl  = ch ^ ((ch >> 3) & 7);
      int row = cl >> 3, gr = cl & 7;
      gload16(Acur + (size_t)(arow0 + row) * K_ + k0 + gr * 8, &As[buf][ch * 8]);
    }
  };
  auto stageB = [&](int kt, int buf) {
    const int k0 = kt * BK;
#pragma unroll
    for (int it = 0; it < 2; ++it) {
      int ch  = it * 512 + tid;
      int cl  = ch ^ ((ch >> 3) & 7);
      int row = cl >> 3, gr = cl & 7;
      gload16(Wp + (size_t)(brow0 + row) * K_ + k0 + gr * 8, &Bs[buf][ch * 8]);
    }
  };

  // tiles 0,1,2 (4 loads/thread each)
  stageA(0, 0); stageB(0, 0);
  stageA(1, 1); stageB(1, 1);
  stageA(2, 2); stageB(2, 2);
  __builtin_amdgcn_sched_barrier(0);

  // emb gather for t+1 (8 loads; compiler inserts the xiv wait)
  float ev[2][4];
#pragma unroll
  for (int m = 0; m < 2; ++m)
#pragma unroll
    for (int r = 0; r < 4; ++r)
      ev[m][r] = emb[(size_t)xiv[m][r] * E_ + e];
  __builtin_amdgcn_sched_barrier(0);

  // ---- fragment offsets (swizzled reads) ----
  int aoff[2][2], boff[2][4];
#pragma unroll
  for (int ks = 0; ks < 2; ++ks) {
#pragma unroll
    for (int m = 0; m < 2; ++m) {
      int cl = (wr * 32 + m * 16 + lq) * 8 + ks * 4 + lh;
      aoff[ks][m] = (cl ^ ((cl >> 3) & 7)) * 8;
    }
#pragma unroll
    for (int n = 0; n < 4; ++n) {
      int cl = (wc * 64 + n * 16 + lq) * 8 + ks * 4 + lh;
      boff[ks][n] = (cl ^ ((cl >> 3) & 7)) * 8;
    }
  }

  f32x4 acc[2][4];
#pragma unroll
  for (int m = 0; m < 2; ++m)
#pragma unroll
    for (int n = 0; n < 4; ++n)
      acc[m][n] = (f32x4){0.f, 0.f, 0.f, 0.f};

  auto mfma_iter = [&](int rb) {
    const __hip_bfloat16* Ab = &As[rb][0];
    const __hip_bfloat16* Bb = &Bs[rb][0];
#pragma unroll
    for (int ks = 0; ks < 2; ++ks) {
      bfrag8 af[2], bfr[4];
#pragma unroll
      for (int m = 0; m < 2; ++m) af[m]  = *(const bfrag8*)(Ab + aoff[ks][m]);
#pragma unroll
      for (int n = 0; n < 4; ++n) bfr[n] = *(const bfrag8*)(Bb + boff[ks][n]);
      __builtin_amdgcn_s_setprio(1);
#pragma unroll
      for (int m = 0; m < 2; ++m)
#pragma unroll
        for (int n = 0; n < 4; ++n)
          acc[m][n] = __builtin_amdgcn_mfma_f32_16x16x32_bf16(af[m], bfr[n], acc[m][n], 0, 0, 0);
      __builtin_amdgcn_s_setprio(0);
    }
  };

  // ---- counted-vmcnt pipeline, 16 iters, distance 3 ----
  // ledger (per thread, 4 loads/tile): queue after emb =
  //   [misc(20 done by emb's own wait), t0(4), t1(4), t2(4), emb(8)]
  WAITVM(16); SBAR(); stageA(3, 3);  stageB(3, 3);  mfma_iter(0);  // t0 done
  WAITVM(16); SBAR(); stageA(4, 0);  stageB(4, 0);  mfma_iter(1);  // t1 done
  WAITVM(16); SBAR(); stageA(5, 1);  stageB(5, 1);  mfma_iter(2);  // t2 done
  WAITVM(8);  SBAR(); stageA(6, 2);  stageB(6, 2);  mfma_iter(3);  // emb+t3 done
#pragma unroll 1
  for (int kt = 4; kt <= 12; ++kt) {
    WAITVM(8); SBAR();
    stageA(kt + 3, (kt + 3) & 3); stageB(kt + 3, (kt + 3) & 3);
    mfma_iter(kt & 3);
  }
  WAITVM(8); SBAR(); mfma_iter(1);   // t13
  WAITVM(4); SBAR(); mfma_iter(2);   // t14
  WAITVM(0); SBAR(); mfma_iter(3);   // t15

  // ---- register epilogue ----
  const bool last = (t == S_ - 1);
#pragma unroll
  for (int m = 0; m < 2; ++m) {
#pragma unroll
    for (int r = 0; r < 4; ++r) {
      int b = arow0 + wr * 32 + m * 16 + lh * 4 + r;
      float iv = acc[m][0][r] + bg[0];
      float fv = acc[m][1][r] + bg[1];
      float gv = acc[m][2][r] + bg[2];
      float ov = acc[m][3][r] + bg[3];
      size_t cidx = (size_t)b * E_ + e;
      float ig = sigm(iv), fg = sigm(fv), gg = tanh_fast(gv), og = sigm(ov);
      float cn = fg * cold[m][r] + ig * gg;
      c[cidx] = cn;
      float h = og * tanh_fast(cn);
      if (last) {
        out[cidx] = h;
      } else {
        Anext[(size_t)b * K_ + E_ + e] = __float2bfloat16(h);
        Anext[(size_t)b * K_ + e]      = __float2bfloat16(ev[m][r]);
      }
    }
  }
}

extern "C" void kernel_launch(void* const* d_in, const int* in_sizes, int n_in,
                              void* d_out, int out_size, void* d_ws, size_t ws_size,
                              hipStream_t stream) {
  const int*   x   = (const int*)d_in[0];
  const float* emb = (const float*)d_in[1];
  const float* Wih = (const float*)d_in[2];
  const float* Whh = (const float*)d_in[3];
  const float* bih = (const float*)d_in[4];
  const float* bhh = (const float*)d_in[5];
  float* out = (float*)d_out;
  (void)in_sizes; (void)n_in; (void)out_size; (void)ws_size;

  char* p = (char*)d_ws;
  __hip_bfloat16* Wp    = (__hip_bfloat16*)p;  p += (size_t)NG * K_ * 2;  // 4 MB
  float*          biasP = (float*)p;           p += (size_t)NG * 4;       // 8 KB
  float*          c     = (float*)p;           p += (size_t)B_ * E_ * 4;  // 4 MB
  __hip_bfloat16* A0    = (__hip_bfloat16*)p;  p += (size_t)B_ * K_ * 2;  // 4 MB
  __hip_bfloat16* A1    = (__hip_bfloat16*)p;  p += (size_t)B_ * K_ * 2;  // 4 MB

  prep_weights<<<NG, 256, 0, stream>>>(Wih, Whh, bih, bhh, Wp, biasP);
  init_state<<<B_, 256, 0, stream>>>(x, emb, c, A0);
  for (int t = 0; t < S_; ++t) {
    __hip_bfloat16* Ac = (t & 1) ? A1 : A0;
    __hip_bfloat16* An = (t & 1) ? A0 : A1;
    lstm_step<<<256, 512, 0, stream>>>(Ac, An, Wp, biasP, c, x, emb, out, t);
  }
}